// Round 18
// baseline (77.490 us; speedup 1.0000x reference)
//
#include <hip/hip_runtime.h>

// Periodogram: out[b,m] = (re^2 + im^2)/N,  re = aC + bS, im = bC - aS
// r18: r16 chassis (barrier-free, wave-private LDS DMA double-buffer) with
// 32x32x16 MFMA (2495 vs 2075 TF ceiling, half the issue slots).
// A/B staged via per-lane DMA source addresses (LDS = 16B/lane conduit);
// trig B-operand in registers: state + Delta16 (kh) + Delta32 (step) rotations.

typedef __fp16 half8  __attribute__((ext_vector_type(8)));
typedef __fp16 half2v __attribute__((ext_vector_type(2)));
typedef float  f32x16 __attribute__((ext_vector_type(16)));

#define B_SZ 512
#define N_SZ 1024
#define M_SZ 16384
#define BT 128
#define MT 128
#define KT 32
#define NT (N_SZ / KT)
#define WS_ARR 1048576   // bytes per converted array (512*1024*2)

union U4 { half2v h2[4]; uint4 u; };
union BF { half2v h2[4]; half8 v; uint4 u; };

__device__ __forceinline__ void gld16(const void* g, void* l) {
    __builtin_amdgcn_global_load_lds((__attribute__((address_space(1))) void*)g,
                                     (__attribute__((address_space(3))) void*)l,
                                     16, 0, 0);
}

// ---- pre-kernel: x (f32) -> d_ws (f16, fragment-tiled 16-row x 32-k, 1KB) ----
__global__ __launch_bounds__(256)
void cvt_kernel(const float* __restrict__ x, unsigned char* __restrict__ ws) {
    const int id  = (int)blockIdx.x * 256 + (int)threadIdx.x;  // 0..131071
    const int arr = id >> 16;            // 0=a, 1=b
    const int rem = id & 65535;
    const int rb  = rem >> 11;           // row block 0..31
    const int kc  = (rem >> 6) & 31;     // k chunk 0..31
    const int l6  = rem & 63;
    const int r16 = l6 >> 2;             // row in block
    const int g   = l6 & 3;              // k sub-group
    const float* src = x + (size_t)(rb * 16 + r16) * 2048 + arr * 1024 + kc * 32 + g * 8;
    const float4 v0 = *(const float4*)src;
    const float4 v1 = *(const float4*)(src + 4);
    U4 u;
    u.h2[0] = __builtin_amdgcn_cvt_pkrtz(v0.x, v0.y);
    u.h2[1] = __builtin_amdgcn_cvt_pkrtz(v0.z, v0.w);
    u.h2[2] = __builtin_amdgcn_cvt_pkrtz(v1.x, v1.y);
    u.h2[3] = __builtin_amdgcn_cvt_pkrtz(v1.z, v1.w);
    *(uint4*)(ws + (size_t)arr * WS_ARR + (size_t)(rb * 32 + kc) * 1024 + (g * 16 + r16) * 16) = u.u;
}

__global__ __launch_bounds__(256, 2)
void periodogram_kernel(const unsigned char* __restrict__ ws,
                        const float* __restrict__ xgrid,
                        float* __restrict__ out) {
    // 4 waves x 2 buffers x 8 KB (A frags 0..4K, B frags 4K..8K), wave-private
    __shared__ __align__(16) unsigned char smem[65536];
    const int tid  = (int)threadIdx.x;
    const int lane = tid & 63;
    const int w    = tid >> 6;
    const int bid  = (int)blockIdx.x;
    const int b0 = (bid & 3) * BT;
    const int m0 = (bid >> 2) * MT;

    const int wr = (w >> 1) * 64;   // wave row offset in tile
    const int wc = (w & 1) * 64;    // wave col offset in tile

    unsigned char* lb = smem + (unsigned)(w * 16384);

    // ---- per-lane A-side source addresses for 32x32x16 fragments ----
    // frag lane l: row = fm*32 + (l&31), k = kh*16 + (l>>5)*8 + j
    // ws tile (rb16 = row>>4, kc = t): byte = kh*512 + ((l>>5)*16 + (l&15))*16
    const int l15 = lane & 15;
    const int l45 = (lane >> 4) & 1;
    const int l5  = lane >> 5;
    const unsigned cellB = (unsigned)(((l5 << 4) + l15) << 4);
    const unsigned char* pA[2];
#pragma unroll
    for (int fm = 0; fm < 2; ++fm) {
        const int rb16 = ((b0 + wr) >> 4) + fm * 2 + l45;
        pA[fm] = ws + (size_t)(rb16 * 32) * 1024 + cellB;
    }

    // ---- per-lane trig state for the B operand (register-resident) ----
    // lane: col = wc + fn*32 + (lane&31), k = kh*16 + (l>>5)*8 + j, +32 per step
    half2v PC[2][4], PS[2][4];
    float c0v[2], s0v[2], C16[2], S16[2], C32[2], S32[2];
    const float g8f = (float)(l5 << 3);
#pragma unroll
    for (int fn = 0; fn < 2; ++fn) {
        const float xg = xgrid[m0 + wc + fn * 32 + (lane & 31)];
        float Cj[8], Sj[8];
        Cj[0] = 1.0f; Sj[0] = 0.0f;
#pragma unroll
        for (int j = 1; j < 8; ++j) {
            float p = xg * (float)j; p -= floorf(p);
            Cj[j] = __builtin_amdgcn_cosf(p);   // cos(2*pi*p)
            Sj[j] = __builtin_amdgcn_sinf(p);
        }
#pragma unroll
        for (int i = 0; i < 4; ++i) {
            PC[fn][i] = __builtin_amdgcn_cvt_pkrtz(Cj[2 * i], Cj[2 * i + 1]);
            PS[fn][i] = __builtin_amdgcn_cvt_pkrtz(Sj[2 * i], Sj[2 * i + 1]);
        }
        float p16 = xg * 16.0f; p16 -= floorf(p16);      // exact product
        C16[fn] = __builtin_amdgcn_cosf(p16);
        S16[fn] = __builtin_amdgcn_sinf(p16);
        float p32 = xg * 32.0f; p32 -= floorf(p32);
        C32[fn] = __builtin_amdgcn_cosf(p32);
        S32[fn] = __builtin_amdgcn_sinf(p32);
        float pb = xg * g8f; pb -= floorf(pb);
        c0v[fn] = __builtin_amdgcn_cosf(pb);
        s0v[fn] = __builtin_amdgcn_sinf(pb);
    }

    f32x16 accRe[2][2], accIm[2][2];
#pragma unroll
    for (int i = 0; i < 2; ++i)
#pragma unroll
        for (int j = 0; j < 2; ++j) { accRe[i][j] = (f32x16)0.0f; accIm[i][j] = (f32x16)0.0f; }

    // ---- prologue: DMA-stage t=0 into buffer 0 (wave-private) ----
    // LDS slot (fm*2+kh)*1024 for A, 4096 + same for B
#pragma unroll
    for (int fm = 0; fm < 2; ++fm)
#pragma unroll
        for (int kh = 0; kh < 2; ++kh) {
            gld16(pA[fm] + kh * 512,          lb + (unsigned)((fm * 2 + kh) * 1024));
            gld16(pA[fm] + WS_ARR + kh * 512, lb + (unsigned)(4096 + (fm * 2 + kh) * 1024));
        }

    for (int t = 0; t < NT; ++t) {
        const unsigned cb = (unsigned)(t & 1) * 8192u;
        // current buffer's DMA complete (wave-private vmcnt)
        asm volatile("s_waitcnt vmcnt(0)" ::: "memory");
        // ---- ds_read fragments (lane-linear b128, conflict-free) ----
        half8 fa[2][2], fbb[2][2];
#pragma unroll
        for (int fm = 0; fm < 2; ++fm)
#pragma unroll
            for (int kh = 0; kh < 2; ++kh) {
                fa[fm][kh]  = *(const half8*)(lb + cb + (unsigned)((fm * 2 + kh) * 1024) + (unsigned)(lane * 16));
                fbb[fm][kh] = *(const half8*)(lb + cb + (unsigned)(4096 + (fm * 2 + kh) * 1024) + (unsigned)(lane * 16));
            }
        // ---- issue next step's DMA into the other buffer ----
        if (t < NT - 1) {
            const unsigned nb = cb ^ 8192u;
            const unsigned off = (unsigned)((t + 1) * 1024);
#pragma unroll
            for (int fm = 0; fm < 2; ++fm)
#pragma unroll
                for (int kh = 0; kh < 2; ++kh) {
                    gld16(pA[fm] + off + kh * 512,          lb + nb + (unsigned)((fm * 2 + kh) * 1024));
                    gld16(pA[fm] + WS_ARR + off + kh * 512, lb + nb + (unsigned)(4096 + (fm * 2 + kh) * 1024));
                }
        }
        // ---- compute: trig in registers + 32 MFMA (32x32x16) ----
#pragma unroll
        for (int fn = 0; fn < 2; ++fn) {
            const float c0 = c0v[fn], s0 = s0v[fn];
            // kh=0 fragments from base state
            const half2v c0b = __builtin_amdgcn_cvt_pkrtz(c0, c0);
            const half2v s0b = __builtin_amdgcn_cvt_pkrtz(s0, s0);
            BF fc0, fs0, fns0, fc1, fs1, fns1;
#pragma unroll
            for (int i = 0; i < 4; ++i) {
                fc0.h2[i] = c0b * PC[fn][i] - s0b * PS[fn][i];
                fs0.h2[i] = s0b * PC[fn][i] + c0b * PS[fn][i];
            }
            // kh=1 state = base rotated by Delta-16
            const float c1 = __builtin_fmaf(c0, C16[fn], -(s0 * S16[fn]));
            const float s1 = __builtin_fmaf(s0, C16[fn],  (c0 * S16[fn]));
            const half2v c1b = __builtin_amdgcn_cvt_pkrtz(c1, c1);
            const half2v s1b = __builtin_amdgcn_cvt_pkrtz(s1, s1);
#pragma unroll
            for (int i = 0; i < 4; ++i) {
                fc1.h2[i] = c1b * PC[fn][i] - s1b * PS[fn][i];
                fs1.h2[i] = s1b * PC[fn][i] + c1b * PS[fn][i];
            }
            fns0.u.x = fs0.u.x ^ 0x80008000u; fns0.u.y = fs0.u.y ^ 0x80008000u;
            fns0.u.z = fs0.u.z ^ 0x80008000u; fns0.u.w = fs0.u.w ^ 0x80008000u;
            fns1.u.x = fs1.u.x ^ 0x80008000u; fns1.u.y = fs1.u.y ^ 0x80008000u;
            fns1.u.z = fs1.u.z ^ 0x80008000u; fns1.u.w = fs1.u.w ^ 0x80008000u;
            __builtin_amdgcn_s_setprio(1);
            // pass 1: C-products (RAW distance 4 between kh0/kh1 on same acc)
#pragma unroll
            for (int fm = 0; fm < 2; ++fm) {
                accRe[fm][fn] = __builtin_amdgcn_mfma_f32_32x32x16_f16(fa[fm][0],  fc0.v, accRe[fm][fn], 0, 0, 0);
                accIm[fm][fn] = __builtin_amdgcn_mfma_f32_32x32x16_f16(fbb[fm][0], fc0.v, accIm[fm][fn], 0, 0, 0);
            }
#pragma unroll
            for (int fm = 0; fm < 2; ++fm) {
                accRe[fm][fn] = __builtin_amdgcn_mfma_f32_32x32x16_f16(fa[fm][1],  fc1.v, accRe[fm][fn], 0, 0, 0);
                accIm[fm][fn] = __builtin_amdgcn_mfma_f32_32x32x16_f16(fbb[fm][1], fc1.v, accIm[fm][fn], 0, 0, 0);
            }
            // pass 2: S-products
#pragma unroll
            for (int fm = 0; fm < 2; ++fm) {
                accRe[fm][fn] = __builtin_amdgcn_mfma_f32_32x32x16_f16(fbb[fm][0], fs0.v,  accRe[fm][fn], 0, 0, 0);
                accIm[fm][fn] = __builtin_amdgcn_mfma_f32_32x32x16_f16(fa[fm][0],  fns0.v, accIm[fm][fn], 0, 0, 0);
            }
#pragma unroll
            for (int fm = 0; fm < 2; ++fm) {
                accRe[fm][fn] = __builtin_amdgcn_mfma_f32_32x32x16_f16(fbb[fm][1], fs1.v,  accRe[fm][fn], 0, 0, 0);
                accIm[fm][fn] = __builtin_amdgcn_mfma_f32_32x32x16_f16(fa[fm][1],  fns1.v, accIm[fm][fn], 0, 0, 0);
            }
            __builtin_amdgcn_s_setprio(0);
            // advance base state by Delta-k = 32 (f32, depth-2)
            c0v[fn] = __builtin_fmaf(c0, C32[fn], -(s0 * S32[fn]));
            s0v[fn] = __builtin_fmaf(s0, C32[fn],  (c0 * S32[fn]));
        }
    }

    // ---- epilogue: out = (re^2 + im^2)/N ----
    // 32x32 C/D layout (measured m74/m101): col = lane&31,
    // row = (reg&3) + 8*(reg>>2) + 4*(lane>>5)
    const float inv = 1.0f / (float)N_SZ;
#pragma unroll
    for (int fm = 0; fm < 2; ++fm)
#pragma unroll
        for (int fn = 0; fn < 2; ++fn) {
            const f32x16 r = accRe[fm][fn];
            const f32x16 im = accIm[fm][fn];
            const int col = m0 + wc + fn * 32 + (lane & 31);
            const int rowbase = b0 + wr + fm * 32 + (l5 << 2);
#pragma unroll
            for (int reg = 0; reg < 16; ++reg) {
                const int row = rowbase + (reg & 3) + ((reg >> 2) << 3);
                out[(size_t)row * M_SZ + col] = (r[reg] * r[reg] + im[reg] * im[reg]) * inv;
            }
        }
}

extern "C" void kernel_launch(void* const* d_in, const int* in_sizes, int n_in,
                              void* d_out, int out_size, void* d_ws, size_t ws_size,
                              hipStream_t stream) {
    const float* x     = (const float*)d_in[0];
    const float* xgrid = (const float*)d_in[1];
    float* out = (float*)d_out;
    unsigned char* ws = (unsigned char*)d_ws;
    // pre-convert x -> f16 fragment-tiled (2 MB in d_ws)
    cvt_kernel<<<512, 256, 0, stream>>>(x, ws);
    dim3 grid(B_SZ / BT * (M_SZ / MT));   // 4 * 128 = 512 blocks
    dim3 block(256);
    periodogram_kernel<<<grid, block, 0, stream>>>(ws, xgrid, out);
}